// Round 6
// baseline (527.667 us; speedup 1.0000x reference)
//
#include <hip/hip_runtime.h>

typedef short v8s __attribute__((ext_vector_type(8)));
typedef float v4f __attribute__((ext_vector_type(4)));

__device__ __forceinline__ unsigned rne_hi(float f) {
    unsigned u = __float_as_uint(f);
    return u + 0x7FFFu + ((u >> 16) & 1u);
}

#if defined(__has_builtin)
#if __has_builtin(__builtin_amdgcn_cvt_pk_bf16_f32)
#define HAVE_PK_BF16 1
#endif
#endif

__device__ __forceinline__ unsigned pk_bf16(float lo, float hi) {
#ifdef HAVE_PK_BF16
    auto r = __builtin_amdgcn_cvt_pk_bf16_f32(lo, hi);
    unsigned u;
    __builtin_memcpy(&u, &r, 4);
    return u;
#else
    return (rne_hi(lo) >> 16) | (rne_hi(hi) & 0xFFFF0000u);
#endif
}

__device__ __forceinline__ void barrier_lgkm() {
    asm volatile("s_waitcnt lgkmcnt(0)\n\ts_barrier" ::: "memory");
}

// ---------------------------------------------------------------------------
// ROUND 6 = ATTRIBUTION PROBE, nt RESTORED (round-2-exact kernels, which
// benched 415.3 us). vconv launched 3x (bit-identical, idempotent -> output
// unchanged). Decodes the 414 us:
//   H-small: dur ~535-585 -> vconv ~60-85 us, harness-fixed ~330 us -> near
//            roofline; next round restores 1x and stops.
//   H-big:   dur ~715-775 -> three ~170 us vconv rows enter rocprof top-5
//            WITH counters -> round 7 attacks what they show.
// Prior two probe attempts died at container acquisition (pre-run infra;
// identical sources passed on other rounds), so failures were content-free.
// ---------------------------------------------------------------------------

// ---------------------------------------------------------------------------
// Pre-pass: X (B=64, C=128, 32, 32) fp32 -> Xt (C, HW, B) bf16, plus a 256 B
// zero page at element 8388608 (OOB unfold taps land there -> no masking).
// ---------------------------------------------------------------------------
__global__ __launch_bounds__(256) void xpose_kernel(const float* __restrict__ X,
                                                    unsigned short* __restrict__ Xt) {
    __shared__ float tile[64][65];
    const int bx  = blockIdx.x;      // 0..2047
    const int c   = bx >> 4;
    const int hw0 = (bx & 15) << 6;
    const int t    = threadIdx.x;
    const int lane = t & 63;
    const int brow = t >> 6;

    if (bx == 0 && t < 128) Xt[8388608 + t] = 0;  // zero page

#pragma unroll
    for (int r = 0; r < 16; ++r) {
        int b = brow + (r << 2);
        tile[b][lane] = __builtin_nontemporal_load(
            &X[((size_t)(b * 128 + c) << 10) + hw0 + lane]);
    }
    __syncthreads();
#pragma unroll
    for (int r = 0; r < 16; ++r) {
        int row = brow + (r << 2);
        float f = tile[lane][row];
        Xt[((((size_t)c << 10) + hw0 + row) << 6) + lane] =
            (unsigned short)(rne_hi(f) >> 16);
    }
}

#define LOADA_SET(KK, P0d, Q0d, P1d, Q1d) do {                                  \
    int kb_ = ((KK) << 6) + (hi4 << 1);                                         \
    int o00_ = tab[kb_], o01_ = tab[kb_ + 1];                                   \
    int o10_ = tab[kb_ + 32], o11_ = tab[kb_ + 33];                             \
    P0d = *(const uint2*)(xb + o00_);                                           \
    Q0d = *(const uint2*)(xb + o01_);                                           \
    P1d = *(const uint2*)(xb + o10_);                                           \
    Q1d = *(const uint2*)(xb + o11_);                                           \
} while (0)

// nt RESTORED (round-5 ablation: removing nt cost +20 us -> keep it).
#define LOADW_SET(KK, FA0d, FB0d, FA1d, FB1d) do {                              \
    const v4f* wb_ = (const v4f*)(wbase + (size_t)(KK) * 4096);                 \
    FA0d = __builtin_nontemporal_load(wb_);                                     \
    FB0d = __builtin_nontemporal_load(wb_ + 16);                                \
    FA1d = __builtin_nontemporal_load(wb_ + 512);                               \
    FB1d = __builtin_nontemporal_load(wb_ + 528);                               \
} while (0)

#define MFMA_H(BUF, H) do {                                                     \
    const unsigned* Ah_ = &A_lds[BUF][H][0];                                    \
    const unsigned* Bh_ = &B_lds[BUF][H][0];                                    \
    v8s a0_ = *(const v8s*)&Ah_[a_raddr[0]];                                    \
    v8s a1_ = *(const v8s*)&Ah_[a_raddr[1]];                                    \
    v8s b0_ = *(const v8s*)&Bh_[b_raddr[0]];                                    \
    v8s b1_ = *(const v8s*)&Bh_[b_raddr[1]];                                    \
    acc[0][0] = __builtin_amdgcn_mfma_f32_16x16x32_bf16(a0_, b0_, acc[0][0], 0, 0, 0); \
    acc[0][1] = __builtin_amdgcn_mfma_f32_16x16x32_bf16(a0_, b1_, acc[0][1], 0, 0, 0); \
    acc[1][0] = __builtin_amdgcn_mfma_f32_16x16x32_bf16(a1_, b0_, acc[1][0], 0, 0, 0); \
    acc[1][1] = __builtin_amdgcn_mfma_f32_16x16x32_bf16(a1_, b1_, acc[1][1], 0, 0, 0); \
} while (0)

#define VBODY(KK, BUF, P0, Q0, P1, Q1, P0n, Q0n, P1n, Q1n, FA0, FB0, FA1, FB1) do { \
    if ((KK) < 17) { LOADA_SET((KK) + 1, P0n, Q0n, P1n, Q1n); }                 \
    {                                                                           \
        unsigned* Ab_ = &A_lds[BUF][0][0];                                      \
        unsigned* Bb_ = &B_lds[BUF][0][0];                                      \
        Bb_[waddr[0]] = pk_bf16(FA0.x, FB0.x);                                  \
        Bb_[waddr[1]] = pk_bf16(FA0.y, FB0.y);                                  \
        Bb_[waddr[2]] = pk_bf16(FA0.z, FB0.z);                                  \
        Bb_[waddr[3]] = pk_bf16(FA0.w, FB0.w);                                  \
        Bb_[1024 + waddr[0]] = pk_bf16(FA1.x, FB1.x);                           \
        Bb_[1024 + waddr[1]] = pk_bf16(FA1.y, FB1.y);                           \
        Bb_[1024 + waddr[2]] = pk_bf16(FA1.z, FB1.z);                           \
        Bb_[1024 + waddr[3]] = pk_bf16(FA1.w, FB1.w);                           \
        Ab_[waddr[0]] = __builtin_amdgcn_perm(Q0.x, P0.x, 0x05040100u);         \
        Ab_[waddr[1]] = __builtin_amdgcn_perm(Q0.x, P0.x, 0x07060302u);         \
        Ab_[waddr[2]] = __builtin_amdgcn_perm(Q0.y, P0.y, 0x05040100u);         \
        Ab_[waddr[3]] = __builtin_amdgcn_perm(Q0.y, P0.y, 0x07060302u);         \
        Ab_[1024 + waddr[0]] = __builtin_amdgcn_perm(Q1.x, P1.x, 0x05040100u);  \
        Ab_[1024 + waddr[1]] = __builtin_amdgcn_perm(Q1.x, P1.x, 0x07060302u);  \
        Ab_[1024 + waddr[2]] = __builtin_amdgcn_perm(Q1.y, P1.y, 0x05040100u);  \
        Ab_[1024 + waddr[3]] = __builtin_amdgcn_perm(Q1.y, P1.y, 0x07060302u);  \
        cs0 += (FA0.x + FB0.x) + (FA1.x + FB1.x);                               \
        cs1 += (FA0.y + FB0.y) + (FA1.y + FB1.y);                               \
        cs2 += (FA0.z + FB0.z) + (FA1.z + FB1.z);                               \
        cs3 += (FA0.w + FB0.w) + (FA1.w + FB1.w);                               \
        if ((KK) < 16) { LOADW_SET((KK) + 2, FA0, FB0, FA1, FB1); }             \
    }                                                                           \
    barrier_lgkm();                                                             \
    MFMA_H(BUF, 0);                                                             \
    MFMA_H(BUF, 1);                                                             \
} while (0)

__global__ __launch_bounds__(256, 4) void vconv_kernel(
    const float* __restrict__ Wg,            // (1024, 1152, 64) fp32
    const float* __restrict__ bias,          // (1024) fp32
    const unsigned short* __restrict__ Xt,   // (128, 1024, 64) bf16 + zero page
    unsigned short* __restrict__ scratch)    // (1024, 4096) bf16, s-major
{
    __shared__ __align__(16) unsigned A_lds[2][2][1024];
    __shared__ __align__(16) unsigned B_lds[2][2][1024];
    __shared__ int tab[1152];

    const int s = blockIdx.x;
    const int y = s >> 5, x = s & 31;
    const int t    = threadIdx.x;
    const int lane = t & 63;
    const int wv   = t >> 6;
    const int mh   = wv >> 1, nh = wv & 1;

    // unfold table: k -> byte offset in Xt (OOB -> zero page at 16777216)
    for (int k = t; k < 1152; k += 256) {
        int c  = k / 9;
        int r  = k - c * 9;
        int di = r / 3, dj = r - di * 3;
        int yy = y + di - 1, xx = x + dj - 1;
        int off = ((c << 10) + (yy << 5) + xx) << 7;
        bool ok = (yy >= 0) && (yy < 32) && (xx >= 0) && (xx < 32);
        tab[k] = ok ? off : 16777216;
    }

    const float bias_s = bias[s];

    const int g16 = t & 15;
    const int hi4 = t >> 4;
    const int r4  = g16 << 2;

    const float* wbase = Wg + ((size_t)s * 1152 + (hi4 << 1)) * 64 + r4;
    const char*  xb    = (const char*)Xt + (r4 << 1);

    unsigned waddr[4];
#pragma unroll
    for (int i = 0; i < 4; ++i) {
        int row = r4 + i;
        unsigned grp = (unsigned)((hi4 >> 2) ^ ((row >> 2) & 3));
        waddr[i] = (unsigned)(row << 4) + (grp << 2) + (unsigned)(hi4 & 3);
    }

    const int quad = lane >> 4, l15 = lane & 15;
    unsigned a_raddr[2], b_raddr[2];
#pragma unroll
    for (int i = 0; i < 2; ++i) {
        int ra = (((mh << 1) + i) << 4) + l15;
        a_raddr[i] = (unsigned)(ra << 4) + ((unsigned)(quad ^ ((ra >> 2) & 3)) << 2);
        int rb = (((nh << 1) + i) << 4) + l15;
        b_raddr[i] = (unsigned)(rb << 4) + ((unsigned)(quad ^ ((rb >> 2) & 3)) << 2);
    }

    v4f acc[2][2];
#pragma unroll
    for (int i = 0; i < 2; ++i)
#pragma unroll
        for (int j = 0; j < 2; ++j) acc[i][j] = (v4f){0.f, 0.f, 0.f, 0.f};
    float cs0 = 0.f, cs1 = 0.f, cs2 = 0.f, cs3 = 0.f;

    barrier_lgkm();  // tab visible to all waves

    uint2 P0a, Q0a, P1a, Q1a, P0b, Q0b, P1b, Q1b;
    v4f FA0a, FB0a, FA1a, FB1a, FA0b, FB0b, FA1b, FB1b;

    LOADA_SET(0, P0a, Q0a, P1a, Q1a);          // oldest in vmem queue
    LOADW_SET(0, FA0a, FB0a, FA1a, FB1a);
    LOADW_SET(1, FA0b, FB0b, FA1b, FB1b);

    for (int kk = 0; kk < 18; kk += 2) {
        VBODY(kk,     0, P0a, Q0a, P1a, Q1a, P0b, Q0b, P1b, Q1b, FA0a, FB0a, FA1a, FB1a);
        VBODY(kk + 1, 1, P0b, Q0b, P1b, Q1b, P0a, Q0a, P1a, Q1a, FA0b, FB0b, FA1b, FB1b);
    }

    // ---- bias * column-sum term (LDS aliased into A_lds[0]; its last reader
    // was MFMA(16), complete before barrier(17) which every wave has passed)
    float (*csum)[65]  = (float (*)[65]) & A_lds[0][0][0];
    float* csum_tot    = ((float*)&A_lds[0][0][0]) + 16 * 65;
    csum[hi4][r4 + 0] = cs0;
    csum[hi4][r4 + 1] = cs1;
    csum[hi4][r4 + 2] = cs2;
    csum[hi4][r4 + 3] = cs3;
    barrier_lgkm();
    if (t < 64) {
        float tot = 0.f;
#pragma unroll
        for (int p = 0; p < 16; ++p) tot += csum[p][t];
        csum_tot[t] = tot;
    }
    barrier_lgkm();

    // ---- epilogue: contiguous (s, mm) bf16 scratch writes
    unsigned short* sb = scratch + ((size_t)s << 12);
#pragma unroll
    for (int j = 0; j < 2; ++j) {
        int n = (((nh << 1) + j) << 4) + l15;
        float cb = bias_s * csum_tot[n];
#pragma unroll
        for (int i = 0; i < 2; ++i) {
#pragma unroll
            for (int r = 0; r < 4; ++r) {
                int m = (((mh << 1) + i) << 4) + (quad << 2) + r;
                sb[(m << 6) + n] = (unsigned short)(rne_hi(acc[i][j][r] + cb) >> 16);
            }
        }
    }
}

// ---------------------------------------------------------------------------
// scratch (s, mm) bf16 -> out (mm, s) fp32, mm = b*64 + c. 64x64 transpose.
// ---------------------------------------------------------------------------
__global__ __launch_bounds__(256) void otrans_kernel(const unsigned short* __restrict__ S,
                                                     float* __restrict__ out) {
    __shared__ unsigned short tile[64][66];
    const int bx = blockIdx.x;       // 0..1023
    const int m0 = (bx & 63) << 6;
    const int s0 = (bx >> 6) << 6;
    const int t = threadIdx.x, lane = t & 63, brow = t >> 6;
#pragma unroll
    for (int r = 0; r < 16; ++r) {
        int row = brow + (r << 2);
        tile[row][lane] = S[((size_t)(s0 + row) << 12) + m0 + lane];
    }
    __syncthreads();
#pragma unroll
    for (int r = 0; r < 16; ++r) {
        int row = brow + (r << 2);
        float f = __uint_as_float((unsigned)tile[lane][row] << 16);
        __builtin_nontemporal_store(f, &out[((size_t)(m0 + row) << 10) + s0 + lane]);
    }
}

// ---------------------------------------------------------------------------
extern "C" void kernel_launch(void* const* d_in, const int* in_sizes, int n_in,
                              void* d_out, int out_size, void* d_ws, size_t ws_size,
                              hipStream_t stream) {
    const float* X    = (const float*)d_in[0];  // (64,128,32,32)
    const float* Wg   = (const float*)d_in[1];  // (1024,1152,64)
    const float* bias = (const float*)d_in[2];  // (32,32)
    float* out = (float*)d_out;                 // (64,64,32,32)

    unsigned short* Xt = (unsigned short*)d_ws;                    // 16 MB + zero page
    unsigned short* scratch = (unsigned short*)((char*)d_ws + 16777472);  // (1024,4096) bf16

    xpose_kernel<<<2048, 256, 0, stream>>>(X, Xt);
    // ATTRIBUTION PROBE: vconv launched 3x (identical work; scratch simply
    // rewritten with identical bytes). (dur - 415)/2 = one vconv duration.
    // If vconv >= ~180us its dispatches surface in rocprof top-5 w/ counters.
    vconv_kernel<<<1024, 256, 0, stream>>>(Wg, bias, Xt, scratch);
    vconv_kernel<<<1024, 256, 0, stream>>>(Wg, bias, Xt, scratch);
    vconv_kernel<<<1024, 256, 0, stream>>>(Wg, bias, Xt, scratch);
    otrans_kernel<<<1024, 256, 0, stream>>>(scratch, out);
}

// Round 7
// 414.609 us; speedup vs baseline: 1.2727x; 1.2727x over previous
//
#include <hip/hip_runtime.h>

typedef short v8s __attribute__((ext_vector_type(8)));
typedef float v4f __attribute__((ext_vector_type(4)));

__device__ __forceinline__ unsigned rne_hi(float f) {
    unsigned u = __float_as_uint(f);
    return u + 0x7FFFu + ((u >> 16) & 1u);
}

#if defined(__has_builtin)
#if __has_builtin(__builtin_amdgcn_cvt_pk_bf16_f32)
#define HAVE_PK_BF16 1
#endif
#endif

__device__ __forceinline__ unsigned pk_bf16(float lo, float hi) {
#ifdef HAVE_PK_BF16
    auto r = __builtin_amdgcn_cvt_pk_bf16_f32(lo, hi);
    unsigned u;
    __builtin_memcpy(&u, &r, 4);
    return u;
#else
    return (rne_hi(lo) >> 16) | (rne_hi(hi) & 0xFFFF0000u);
#endif
}

__device__ __forceinline__ void barrier_lgkm() {
    asm volatile("s_waitcnt lgkmcnt(0)\n\ts_barrier" ::: "memory");
}

// ---------------------------------------------------------------------------
// ROUND 7 = FINAL: round-2-validated pipeline restored (1x vconv, nt weight
// loads). Session attribution (round-6 probe): vconv ~= 56 us vs 48 us
// weight-BW floor (302 MB fp32 / 6.55 TB/s); xpose+otrans ~= 15 us; the
// remaining ~340 us of dur_us is harness-fixed fill/restore traffic.
// Controllable headroom <= ~10 us (~2.5% of total) -> roofline.
// Keep: nt on weight loads (ablation round 5: removing it = +20 us, L2
// pollution of the Xt gather). Keep: 1-barrier double-buffered schedule.
// ---------------------------------------------------------------------------

// ---------------------------------------------------------------------------
// Pre-pass: X (B=64, C=128, 32, 32) fp32 -> Xt (C, HW, B) bf16, plus a 256 B
// zero page at element 8388608 (OOB unfold taps land there -> no masking).
// ---------------------------------------------------------------------------
__global__ __launch_bounds__(256) void xpose_kernel(const float* __restrict__ X,
                                                    unsigned short* __restrict__ Xt) {
    __shared__ float tile[64][65];
    const int bx  = blockIdx.x;      // 0..2047
    const int c   = bx >> 4;
    const int hw0 = (bx & 15) << 6;
    const int t    = threadIdx.x;
    const int lane = t & 63;
    const int brow = t >> 6;

    if (bx == 0 && t < 128) Xt[8388608 + t] = 0;  // zero page

#pragma unroll
    for (int r = 0; r < 16; ++r) {
        int b = brow + (r << 2);
        tile[b][lane] = __builtin_nontemporal_load(
            &X[((size_t)(b * 128 + c) << 10) + hw0 + lane]);
    }
    __syncthreads();
#pragma unroll
    for (int r = 0; r < 16; ++r) {
        int row = brow + (r << 2);
        float f = tile[lane][row];
        Xt[((((size_t)c << 10) + hw0 + row) << 6) + lane] =
            (unsigned short)(rne_hi(f) >> 16);
    }
}

#define LOADA_SET(KK, P0d, Q0d, P1d, Q1d) do {                                  \
    int kb_ = ((KK) << 6) + (hi4 << 1);                                         \
    int o00_ = tab[kb_], o01_ = tab[kb_ + 1];                                   \
    int o10_ = tab[kb_ + 32], o11_ = tab[kb_ + 33];                             \
    P0d = *(const uint2*)(xb + o00_);                                           \
    Q0d = *(const uint2*)(xb + o01_);                                           \
    P1d = *(const uint2*)(xb + o10_);                                           \
    Q1d = *(const uint2*)(xb + o11_);                                           \
} while (0)

// nt on weight loads: streamed-once data; ablation showed removing it costs
// +20 us (weight stream evicts L2-resident Xt working set).
#define LOADW_SET(KK, FA0d, FB0d, FA1d, FB1d) do {                              \
    const v4f* wb_ = (const v4f*)(wbase + (size_t)(KK) * 4096);                 \
    FA0d = __builtin_nontemporal_load(wb_);                                     \
    FB0d = __builtin_nontemporal_load(wb_ + 16);                                \
    FA1d = __builtin_nontemporal_load(wb_ + 512);                               \
    FB1d = __builtin_nontemporal_load(wb_ + 528);                               \
} while (0)

#define MFMA_H(BUF, H) do {                                                     \
    const unsigned* Ah_ = &A_lds[BUF][H][0];                                    \
    const unsigned* Bh_ = &B_lds[BUF][H][0];                                    \
    v8s a0_ = *(const v8s*)&Ah_[a_raddr[0]];                                    \
    v8s a1_ = *(const v8s*)&Ah_[a_raddr[1]];                                    \
    v8s b0_ = *(const v8s*)&Bh_[b_raddr[0]];                                    \
    v8s b1_ = *(const v8s*)&Bh_[b_raddr[1]];                                    \
    acc[0][0] = __builtin_amdgcn_mfma_f32_16x16x32_bf16(a0_, b0_, acc[0][0], 0, 0, 0); \
    acc[0][1] = __builtin_amdgcn_mfma_f32_16x16x32_bf16(a0_, b1_, acc[0][1], 0, 0, 0); \
    acc[1][0] = __builtin_amdgcn_mfma_f32_16x16x32_bf16(a1_, b0_, acc[1][0], 0, 0, 0); \
    acc[1][1] = __builtin_amdgcn_mfma_f32_16x16x32_bf16(a1_, b1_, acc[1][1], 0, 0, 0); \
} while (0)

#define VBODY(KK, BUF, P0, Q0, P1, Q1, P0n, Q0n, P1n, Q1n, FA0, FB0, FA1, FB1) do { \
    if ((KK) < 17) { LOADA_SET((KK) + 1, P0n, Q0n, P1n, Q1n); }                 \
    {                                                                           \
        unsigned* Ab_ = &A_lds[BUF][0][0];                                      \
        unsigned* Bb_ = &B_lds[BUF][0][0];                                      \
        Bb_[waddr[0]] = pk_bf16(FA0.x, FB0.x);                                  \
        Bb_[waddr[1]] = pk_bf16(FA0.y, FB0.y);                                  \
        Bb_[waddr[2]] = pk_bf16(FA0.z, FB0.z);                                  \
        Bb_[waddr[3]] = pk_bf16(FA0.w, FB0.w);                                  \
        Bb_[1024 + waddr[0]] = pk_bf16(FA1.x, FB1.x);                           \
        Bb_[1024 + waddr[1]] = pk_bf16(FA1.y, FB1.y);                           \
        Bb_[1024 + waddr[2]] = pk_bf16(FA1.z, FB1.z);                           \
        Bb_[1024 + waddr[3]] = pk_bf16(FA1.w, FB1.w);                           \
        Ab_[waddr[0]] = __builtin_amdgcn_perm(Q0.x, P0.x, 0x05040100u);         \
        Ab_[waddr[1]] = __builtin_amdgcn_perm(Q0.x, P0.x, 0x07060302u);         \
        Ab_[waddr[2]] = __builtin_amdgcn_perm(Q0.y, P0.y, 0x05040100u);         \
        Ab_[waddr[3]] = __builtin_amdgcn_perm(Q0.y, P0.y, 0x07060302u);         \
        Ab_[1024 + waddr[0]] = __builtin_amdgcn_perm(Q1.x, P1.x, 0x05040100u);  \
        Ab_[1024 + waddr[1]] = __builtin_amdgcn_perm(Q1.x, P1.x, 0x07060302u);  \
        Ab_[1024 + waddr[2]] = __builtin_amdgcn_perm(Q1.y, P1.y, 0x05040100u);  \
        Ab_[1024 + waddr[3]] = __builtin_amdgcn_perm(Q1.y, P1.y, 0x07060302u);  \
        cs0 += (FA0.x + FB0.x) + (FA1.x + FB1.x);                               \
        cs1 += (FA0.y + FB0.y) + (FA1.y + FB1.y);                               \
        cs2 += (FA0.z + FB0.z) + (FA1.z + FB1.z);                               \
        cs3 += (FA0.w + FB0.w) + (FA1.w + FB1.w);                               \
        if ((KK) < 16) { LOADW_SET((KK) + 2, FA0, FB0, FA1, FB1); }             \
    }                                                                           \
    barrier_lgkm();                                                             \
    MFMA_H(BUF, 0);                                                             \
    MFMA_H(BUF, 1);                                                             \
} while (0)

__global__ __launch_bounds__(256, 4) void vconv_kernel(
    const float* __restrict__ Wg,            // (1024, 1152, 64) fp32
    const float* __restrict__ bias,          // (1024) fp32
    const unsigned short* __restrict__ Xt,   // (128, 1024, 64) bf16 + zero page
    unsigned short* __restrict__ scratch)    // (1024, 4096) bf16, s-major
{
    __shared__ __align__(16) unsigned A_lds[2][2][1024];
    __shared__ __align__(16) unsigned B_lds[2][2][1024];
    __shared__ int tab[1152];

    const int s = blockIdx.x;
    const int y = s >> 5, x = s & 31;
    const int t    = threadIdx.x;
    const int lane = t & 63;
    const int wv   = t >> 6;
    const int mh   = wv >> 1, nh = wv & 1;

    // unfold table: k -> byte offset in Xt (OOB -> zero page at 16777216)
    for (int k = t; k < 1152; k += 256) {
        int c  = k / 9;
        int r  = k - c * 9;
        int di = r / 3, dj = r - di * 3;
        int yy = y + di - 1, xx = x + dj - 1;
        int off = ((c << 10) + (yy << 5) + xx) << 7;
        bool ok = (yy >= 0) && (yy < 32) && (xx >= 0) && (xx < 32);
        tab[k] = ok ? off : 16777216;
    }

    const float bias_s = bias[s];

    const int g16 = t & 15;
    const int hi4 = t >> 4;
    const int r4  = g16 << 2;

    const float* wbase = Wg + ((size_t)s * 1152 + (hi4 << 1)) * 64 + r4;
    const char*  xb    = (const char*)Xt + (r4 << 1);

    unsigned waddr[4];
#pragma unroll
    for (int i = 0; i < 4; ++i) {
        int row = r4 + i;
        unsigned grp = (unsigned)((hi4 >> 2) ^ ((row >> 2) & 3));
        waddr[i] = (unsigned)(row << 4) + (grp << 2) + (unsigned)(hi4 & 3);
    }

    const int quad = lane >> 4, l15 = lane & 15;
    unsigned a_raddr[2], b_raddr[2];
#pragma unroll
    for (int i = 0; i < 2; ++i) {
        int ra = (((mh << 1) + i) << 4) + l15;
        a_raddr[i] = (unsigned)(ra << 4) + ((unsigned)(quad ^ ((ra >> 2) & 3)) << 2);
        int rb = (((nh << 1) + i) << 4) + l15;
        b_raddr[i] = (unsigned)(rb << 4) + ((unsigned)(quad ^ ((rb >> 2) & 3)) << 2);
    }

    v4f acc[2][2];
#pragma unroll
    for (int i = 0; i < 2; ++i)
#pragma unroll
        for (int j = 0; j < 2; ++j) acc[i][j] = (v4f){0.f, 0.f, 0.f, 0.f};
    float cs0 = 0.f, cs1 = 0.f, cs2 = 0.f, cs3 = 0.f;

    barrier_lgkm();  // tab visible to all waves

    uint2 P0a, Q0a, P1a, Q1a, P0b, Q0b, P1b, Q1b;
    v4f FA0a, FB0a, FA1a, FB1a, FA0b, FB0b, FA1b, FB1b;

    LOADA_SET(0, P0a, Q0a, P1a, Q1a);          // oldest in vmem queue
    LOADW_SET(0, FA0a, FB0a, FA1a, FB1a);
    LOADW_SET(1, FA0b, FB0b, FA1b, FB1b);

    for (int kk = 0; kk < 18; kk += 2) {
        VBODY(kk,     0, P0a, Q0a, P1a, Q1a, P0b, Q0b, P1b, Q1b, FA0a, FB0a, FA1a, FB1a);
        VBODY(kk + 1, 1, P0b, Q0b, P1b, Q1b, P0a, Q0a, P1a, Q1a, FA0b, FB0b, FA1b, FB1b);
    }

    // ---- bias * column-sum term (LDS aliased into A_lds[0]; its last reader
    // was MFMA(16), complete before barrier(17) which every wave has passed)
    float (*csum)[65]  = (float (*)[65]) & A_lds[0][0][0];
    float* csum_tot    = ((float*)&A_lds[0][0][0]) + 16 * 65;
    csum[hi4][r4 + 0] = cs0;
    csum[hi4][r4 + 1] = cs1;
    csum[hi4][r4 + 2] = cs2;
    csum[hi4][r4 + 3] = cs3;
    barrier_lgkm();
    if (t < 64) {
        float tot = 0.f;
#pragma unroll
        for (int p = 0; p < 16; ++p) tot += csum[p][t];
        csum_tot[t] = tot;
    }
    barrier_lgkm();

    // ---- epilogue: contiguous (s, mm) bf16 scratch writes
    unsigned short* sb = scratch + ((size_t)s << 12);
#pragma unroll
    for (int j = 0; j < 2; ++j) {
        int n = (((nh << 1) + j) << 4) + l15;
        float cb = bias_s * csum_tot[n];
#pragma unroll
        for (int i = 0; i < 2; ++i) {
#pragma unroll
            for (int r = 0; r < 4; ++r) {
                int m = (((mh << 1) + i) << 4) + (quad << 2) + r;
                sb[(m << 6) + n] = (unsigned short)(rne_hi(acc[i][j][r] + cb) >> 16);
            }
        }
    }
}

// ---------------------------------------------------------------------------
// scratch (s, mm) bf16 -> out (mm, s) fp32, mm = b*64 + c. 64x64 transpose.
// ---------------------------------------------------------------------------
__global__ __launch_bounds__(256) void otrans_kernel(const unsigned short* __restrict__ S,
                                                     float* __restrict__ out) {
    __shared__ unsigned short tile[64][66];
    const int bx = blockIdx.x;       // 0..1023
    const int m0 = (bx & 63) << 6;
    const int s0 = (bx >> 6) << 6;
    const int t = threadIdx.x, lane = t & 63, brow = t >> 6;
#pragma unroll
    for (int r = 0; r < 16; ++r) {
        int row = brow + (r << 2);
        tile[row][lane] = S[((size_t)(s0 + row) << 12) + m0 + lane];
    }
    __syncthreads();
#pragma unroll
    for (int r = 0; r < 16; ++r) {
        int row = brow + (r << 2);
        float f = __uint_as_float((unsigned)tile[lane][row] << 16);
        __builtin_nontemporal_store(f, &out[((size_t)(m0 + row) << 10) + s0 + lane]);
    }
}

// ---------------------------------------------------------------------------
extern "C" void kernel_launch(void* const* d_in, const int* in_sizes, int n_in,
                              void* d_out, int out_size, void* d_ws, size_t ws_size,
                              hipStream_t stream) {
    const float* X    = (const float*)d_in[0];  // (64,128,32,32)
    const float* Wg   = (const float*)d_in[1];  // (1024,1152,64)
    const float* bias = (const float*)d_in[2];  // (32,32)
    float* out = (float*)d_out;                 // (64,64,32,32)

    unsigned short* Xt = (unsigned short*)d_ws;                    // 16 MB + zero page
    unsigned short* scratch = (unsigned short*)((char*)d_ws + 16777472);  // (1024,4096) bf16

    xpose_kernel<<<2048, 256, 0, stream>>>(X, Xt);
    vconv_kernel<<<1024, 256, 0, stream>>>(Wg, bias, Xt, scratch);
    otrans_kernel<<<1024, 256, 0, stream>>>(scratch, out);
}